// Round 9
// baseline (164.141 us; speedup 1.0000x reference)
//
#include <hip/hip_runtime.h>
#include <stdint.h>

// ---------------------------------------------------------------------------
// ProteinFeaturesNA on MI355X — R19: all-K single-pass kC, kD deleted.
// Chip-wide lut16 count is set by the rt x fg dedup factor, not KSPLIT, so
// KSPLIT=1 is VALU-free: grid 240 x 512 thr (8 waves), wave w = (rt=w&3,
// fg=w>>2) owns 1 row-tile x 4 fragments, 84 pipelined K-iters + tail.
// Deletes the 15.7 MB Ep round-trip, the kD dispatch, and 4x of the
// jT/LUT staging. LN runs in-block on an LDS f32 [64][132] buffer overlaid
// on the dead jT/tabS region (stride 132 -> 2-way banks = free). All 8
// waves stream the SAME W d-block sequence (L1-shared; R14's mistake
// avoided). R18 budget: fills 88 (harness, fixed) + kPrep 10 (We-read
// floor) + kC 37 + kD 7 + gaps 6.
// Outputs (f32): V[512][128], E[15360][128], E_idx[15360].
// Dispatches: kPrep (aug/V-LN/top30 + W swizzle + LUT gen), kC.
// ---------------------------------------------------------------------------

#define NRES   512
#define TOPK   30
#define NATOM  26
#define KTOT   10832
#define NBLK128 85            // 128-k blocks (padded K = 10880)
#define MTOT   (NRES*TOPK)    // 15360
#define NOUT   128
#define TBINS  1024
#define TRANGE 25.6f          // Ds range covered by table; beyond -> zeros

#define OFF_AUGX4  0u          // 512*26 float4        = 212992
#define OFF_EIDX   212992u     // 512*30 i32           =  61440 -> 274432
#define OFF_WSWZ   274432u     // 85*8 frag * 2048 B   = 1392640 -> 1667072
#define OFF_TAB    1667072u    // 1024 * 16 B fp8 LUT  =    16384 -> 1683456

#define OUT_V     0
#define OUT_E     (NRES*NOUT)            // 65536
#define OUT_EIDX  (OUT_E + MTOT*NOUT)    // 2031616

typedef __attribute__((ext_vector_type(4))) float f32x4;
typedef __attribute__((ext_vector_type(8))) int   i32x8;

#define SA_C    0.96089792702915984f     // sqrt(log2 e)/1.25
#define MU0_C   1.9217958540583197f      // 2*SA
#define MUS_C   1.2811972360388798f      // (4/3)*SA
#define MUS2_C  (MUS_C*MUS_C)
#define SCL1    0x7f7f7f7f               // e8m0 unity scales (any opsel byte)
// LUT: bin = (int)(sqrt(d2) * SA * TBINS/TRANGE), clamped to TBINS-1.
#define TSCL    (SA_C * (float)TBINS / TRANGE)

// kC shared-memory overlay (phase 1: staging+main loop; phase 2: LN buffer)
#define SM_JT    0u            // uint2[26*65]  = 13520
#define SM_IT    13520u        // float4[5*26]  =  2080 -> 15600
#define SM_JROW  15600u        // int[64]       =   256 -> 15856
#define SM_TAB   15856u        // uint4[1024]   = 16384 -> 32240
#define SM_LN    0u            // float[64][132] = 33792 (overlay, phase 2)
#define SM_SIZE  33792u

__device__ __forceinline__ unsigned short f2bf(float f) {
    unsigned u = __builtin_bit_cast(unsigned, f);
    return (unsigned short)((u + 0x7fffu + ((u >> 16) & 1u)) >> 16);
}
__device__ __forceinline__ float bflo(unsigned u) {
    return __builtin_bit_cast(float, u << 16);
}
__device__ __forceinline__ float bfhi(unsigned u) {
    return __builtin_bit_cast(float, u & 0xffff0000u);
}
__device__ __forceinline__ unsigned long long shfl_xor_u64(unsigned long long v, int m) {
    unsigned lo = (unsigned)v, hi = (unsigned)(v >> 32);
    lo = (unsigned)__shfl_xor((int)lo, m, 64);
    hi = (unsigned)__shfl_xor((int)hi, m, 64);
    return ((unsigned long long)hi << 32) | lo;
}
__device__ __forceinline__ float fexp2(float x) { return __builtin_amdgcn_exp2f(x); }
__device__ __forceinline__ float fsqrtf(float x) { return __builtin_amdgcn_sqrtf(x); }

// 16 RBF fp8 features of one slot via LDS LUT: one distance -> one b128 read.
// Bin TBINS-1 is all-zero in fp8. Masking is baked into coordinates:
// masked-j rows sit at -30000, masked-i atoms at +30000, so every masked
// pairing yields a huge distance -> fminf clamps to the last (zero) bin.
__device__ __forceinline__ uint4 lut16(const uint4* __restrict__ tabS,
                                       float4 xi, float jx, float jy, float jz) {
    float dx = xi.x - jx, dy = xi.y - jy, dz = xi.z - jz;
    float d2 = __builtin_fmaf(dx, dx, __builtin_fmaf(dy, dy,
               __builtin_fmaf(dz, dz, 1e-6f)));
    float fi = fsqrtf(d2) * TSCL;            // Ds * (TBINS/TRANGE)
    fi = fminf(fi, (float)(TBINS - 1));
    return tabS[(int)fi];
}

// -------------------------------------------------------------- kernel Prep --
// blocks [0,512): aug atoms + V-LN + top-30; blocks [512,896): W swizzle;
// blocks [896,900): RBF LUT generation (1024 bins x 16 fp8 feats).
// W fragment (K=128 layout): frag (d, nt) = 64 lanes x 32 B; lane
// (qd*16 + (n&15)) bytes cc*16+f = fp8 W[n][slot 8d+2qd+cc, feature f].
__global__ __launch_bounds__(256) void kPrep(
    const float* __restrict__ X, const float* __restrict__ Xm,
    const float* __restrict__ prot, const float* __restrict__ dna,
    const float* __restrict__ rna, const int* __restrict__ ptype,
    const float* __restrict__ Wn, const float* __restrict__ gn,
    const float* __restrict__ bn, const float* __restrict__ We,
    char* __restrict__ ws, float* __restrict__ out)
{
    if (blockIdx.x >= NRES + 384) {
        // LUT generation: one bin per thread. feature f = exp2(-(Ds-mu_f)^2),
        // mu_f = MU0 + f*MUS; Ds at bin center (b+0.5)*TRANGE/TBINS.
        int bb = (blockIdx.x - (NRES + 384)) * 256 + threadIdx.x;
        if (bb >= TBINS) return;
        float Ds = ((float)bb + 0.5f) * (TRANGE / (float)TBINS);
        unsigned r[4];
        #pragma unroll
        for (int g = 0; g < 4; g++) {
            float u0 = Ds - (MU0_C + (float)(4*g + 0) * MUS_C);
            float u1 = Ds - (MU0_C + (float)(4*g + 1) * MUS_C);
            float u2 = Ds - (MU0_C + (float)(4*g + 2) * MUS_C);
            float u3 = Ds - (MU0_C + (float)(4*g + 3) * MUS_C);
            float e0 = fexp2(-(u0 * u0));
            float e1 = fexp2(-(u1 * u1));
            float e2 = fexp2(-(u2 * u2));
            float e3 = fexp2(-(u3 * u3));
            int p = __builtin_amdgcn_cvt_pk_fp8_f32(e0, e1, 0, false);
            p     = __builtin_amdgcn_cvt_pk_fp8_f32(e2, e3, p, true);
            r[g] = (unsigned)p;
        }
        *(uint4*)(ws + OFF_TAB + (size_t)bb * 16) =
            make_uint4(r[0], r[1], r[2], r[3]);
        return;
    }
    if (blockIdx.x >= NRES) {
        int idx = blockIdx.x - NRES;
        int n = idx / 3;
        int s = (idx - n*3)*256 + threadIdx.x;
        if (s >= 677) return;
        const float* src = We + (size_t)n*KTOT + ((s < 676) ? (16 + s*16) : 0);
        float4 v0 = ((const float4*)src)[0];
        float4 v1 = ((const float4*)src)[1];
        float4 v2 = ((const float4*)src)[2];
        float4 v3 = ((const float4*)src)[3];
        int d = s >> 3, sl = s & 7, qd2 = sl >> 1, cc = sl & 1;
        size_t base = OFF_WSWZ
                    + (((size_t)(d*8 + (n >> 4))*64) + (size_t)(qd2*16 + (n & 15)))*32
                    + (size_t)cc*16;
        int r0 = __builtin_amdgcn_cvt_pk_fp8_f32(v0.x, v0.y, 0, false);
        r0     = __builtin_amdgcn_cvt_pk_fp8_f32(v0.z, v0.w, r0, true);
        int r1 = __builtin_amdgcn_cvt_pk_fp8_f32(v1.x, v1.y, 0, false);
        r1     = __builtin_amdgcn_cvt_pk_fp8_f32(v1.z, v1.w, r1, true);
        int r2 = __builtin_amdgcn_cvt_pk_fp8_f32(v2.x, v2.y, 0, false);
        r2     = __builtin_amdgcn_cvt_pk_fp8_f32(v2.z, v2.w, r2, true);
        int r3 = __builtin_amdgcn_cvt_pk_fp8_f32(v3.x, v3.y, 0, false);
        r3     = __builtin_amdgcn_cvt_pk_fp8_f32(v3.z, v3.w, r3, true);
        *(uint4*)(ws + base) = make_uint4((unsigned)r0, (unsigned)r1,
                                          (unsigned)r2, (unsigned)r3);
        return;
    }

    const int i = blockIdx.x, t = threadIdx.x;
    if (t >= 128) return;
    float4* augX4 = (float4*)(ws + OFF_AUGX4);
    int*    Eidx  = (int*)(ws + OFF_EIDX);
    const float* Xi = X + i * 72;

    if (t < 26) {
        float x, y, z, mk;
        if (t < 24) {
            x = Xi[t*3]; y = Xi[t*3+1]; z = Xi[t*3+2];
            mk = Xm[i*24 + t];
        } else if (t == 24) {
            float b0 = Xi[3]-Xi[0], b1 = Xi[4]-Xi[1], b2 = Xi[5]-Xi[2];
            float c0 = Xi[6]-Xi[3], c1 = Xi[7]-Xi[4], c2 = Xi[8]-Xi[5];
            float a0 = b1*c2-b2*c1, a1 = b2*c0-b0*c2, a2 = b0*c1-b1*c0;
            x = -0.58273431f*a0 + 0.56802827f*b0 - 0.54067466f*c0 + Xi[3];
            y = -0.58273431f*a1 + 0.56802827f*b1 - 0.54067466f*c1 + Xi[4];
            z = -0.58273431f*a2 + 0.56802827f*b2 - 0.54067466f*c2 + Xi[5];
            mk = prot[i];
        } else {
            const float* O4 = Xi + 33; const float* C1 = Xi + 45; const float* C2 = Xi + 42;
            float b0 = C1[0]-O4[0], b1 = C1[1]-O4[1], b2 = C1[2]-O4[2];
            float c0 = C2[0]-C1[0], c1 = C2[1]-C1[1], c2 = C2[2]-C1[2];
            float a0 = b1*c2-b2*c1, a1 = b2*c0-b0*c2, a2 = b0*c1-b1*c0;
            x = -0.56967352f*a0 + 0.51055973f*b0 - 0.53122153f*c0 + C1[0];
            y = -0.56967352f*a1 + 0.51055973f*b1 - 0.53122153f*c1 + C1[1];
            z = -0.56967352f*a2 + 0.51055973f*b2 - 0.53122153f*c2 + C1[2];
            mk = dna[i] + rna[i];
        }
        augX4[i*26 + t] = make_float4(x, y, z, mk);
    }

    // V layernorm (128 threads)
    __shared__ float red[4];
    int ty = ptype[i];
    float v = Wn[t*3 + ty];
    float s = v;
    #pragma unroll
    for (int off = 32; off; off >>= 1) s += __shfl_xor(s, off, 64);
    if ((t & 63) == 0) red[t>>6] = s;
    __syncthreads();
    float mean = (red[0] + red[1]) * (1.0f/128.0f);
    float d = v - mean;
    float s2 = d*d;
    #pragma unroll
    for (int off = 32; off; off >>= 1) s2 += __shfl_xor(s2, off, 64);
    if ((t & 63) == 0) red[2 + (t>>6)] = s2;
    __syncthreads();
    float var = (red[2] + red[3]) * (1.0f/128.0f);
    out[OUT_V + i*NOUT + t] = d * rsqrtf(var + 1e-5f) * gn[t] + bn[t];

    // top-30 (wave 0 only); Xc computed inline (bit-identical ops)
    if (t >= 64) return;
    const int l = t;
    float xi0 = Xi[3] + Xi[45], xi1 = Xi[4] + Xi[46], xi2 = Xi[5] + Xi[47];
    unsigned long long cand[8];
    #pragma unroll
    for (int sg = 0; sg < 8; sg++) {
        int j = sg*64 + l;
        const float* Xj = X + j*72;
        float c0 = Xj[3] + Xj[45], c1 = Xj[4] + Xj[46], c2 = Xj[5] + Xj[47];
        float dx = xi0 - c0, dy = xi1 - c1, dz = xi2 - c2;
        float dd = __fadd_rn(__fadd_rn(__fadd_rn(__fmul_rn(dx,dx), __fmul_rn(dy,dy)),
                                       __fmul_rn(dz,dz)), 1e-6f);
        float D = sqrtf(dd);
        cand[sg] = ((unsigned long long)__builtin_bit_cast(unsigned, D) << 32) | (unsigned)j;
    }
    for (int m = 0; m < TOPK; m++) {
        unsigned long long k = cand[0];
        #pragma unroll
        for (int sg = 1; sg < 8; sg++) if (cand[sg] < k) k = cand[sg];
        #pragma unroll
        for (int off = 32; off; off >>= 1) {
            unsigned long long o = shfl_xor_u64(k, off);
            if (o < k) k = o;
        }
        if (l == 0) {
            int j = (int)(k & 0xffffffffu);
            Eidx[i*TOPK + m] = j;
            out[OUT_EIDX + i*TOPK + m] = (float)j;
        }
        #pragma unroll
        for (int sg = 0; sg < 8; sg++) if (cand[sg] == k) cand[sg] = ~0ull;
    }
}

// ---------------------------------------------------------------- kernel C --
// grid (240): block = 8 waves x 64 rows x ALL of K. Wave w = (rt = w&3,
// fg = w>>2): row tile rt (rows bx*64 + rt*16 + mlane), col fragments
// f = fg*4 + nt (nt<4). Lane (mlane, qd) covers k = qd*32..+31 = slots
// 8d+2qd, +1 per 128-k block d; 84 pipelined main iters + tail d=84.
// Epilogue: acc -> LDS f32 [64][132] (overlay on dead jT/tabS), in-block
// LN, final E written once as f32. RBF features from 16 KB LDS LUT.
__global__ __launch_bounds__(512, 2) void kC(const int* __restrict__ Ridx,
                                             const int* __restrict__ chain,
                                             const float* __restrict__ Wp,
                                             const float* __restrict__ bp,
                                             const float* __restrict__ ge,
                                             const float* __restrict__ be,
                                             char* __restrict__ ws,
                                             float* __restrict__ out)
{
    const int bx = blockIdx.x;
    const int t = threadIdx.x, lane = t & 63, w = t >> 6;
    const int mlane = lane & 15, qd = lane >> 4;
    const int rt = w & 3;                 // row tile for this wave
    const int fg = w >> 2;                // fragment group (4 frags)

    const float4* augX4 = (const float4*)(ws + OFF_AUGX4);
    const int*    Eidx  = (const int*)(ws + OFF_EIDX);

    __shared__ char smem[SM_SIZE];
    uint2*  jT    = (uint2*)(smem + SM_JT);     // [26][65] padded
    float4* iT    = (float4*)(smem + SM_IT);    // [5][26]
    int*    JrowS = (int*)(smem + SM_JROW);     // [64]
    uint4*  tabS  = (uint4*)(smem + SM_TAB);    // [1024]
    float*  lnS   = (float*)(smem + SM_LN);     // [64][132] phase-2 overlay

    if (t < 64) JrowS[t] = Eidx[bx*64 + t];
    __syncthreads();
    const int i_base = (bx*64) / TOPK;
    if (t < 5*26) {
        int il_ = t / 26, aa = t - il_*26;
        int gi = i_base + il_; gi = gi > 511 ? 511 : gi;
        float4 v = augX4[(size_t)gi*26 + aa];
        if (v.w == 0.0f) { v.x = 30000.0f; v.y = 30000.0f; v.z = 30000.0f; }
        iT[t] = v;
    }
    {   // stage LUT: 1024 x 16 B, coalesced (L2-resident)
        const uint4* tabG = (const uint4*)(ws + OFF_TAB);
        tabS[t]       = tabG[t];
        tabS[t + 512] = tabG[t + 512];
    }
    for (int wk = t; wk < NATOM*64; wk += 512) {
        int aa = wk >> 6, rl_ = wk & 63;
        float4 p = augX4[(size_t)JrowS[rl_]*26 + aa];
        float x = p.x, y = p.y, z = p.z;
        if (p.w == 0.0f) { x = -30000.0f; y = -30000.0f; z = -30000.0f; }
        uint2 pk;
        pk.x = (unsigned)f2bf(x) | ((unsigned)f2bf(y) << 16);
        pk.y = (unsigned)f2bf(z);
        jT[aa*65 + rl_] = pk;
    }
    __syncthreads();

    const int rl = rt*16 + mlane;                 // row within block
    const int il = ((bx*64 + rl) / TOPK - i_base) * 26;

    f32x4 acc[4];   // [nt]
    #pragma unroll
    for (int nt = 0; nt < 4; nt++)
        acc[nt] = (f32x4){0.f,0.f,0.f,0.f};

    // slot state: s = d*8 + 2*qd = a*26 + rem (d starts at 0)
    int a = (2*qd) / 26, rem = (2*qd) - a*26;     // a=0, rem=2*qd

    // wave reads fragments f = fg*4 + {0..3} (its 64 cols)
    const char* Wb = (const char*)(ws + OFF_WSWZ)
                   + (size_t)(fg*4)*2048 + (size_t)lane*32;

    // software pipeline: b0..b3 hold block d; prefetch d+1 each iter.
    // 84 main iters (d=0..83); after the loop b0..b3 hold the tail d=84.
    i32x8 b0 = *(const i32x8*)(Wb);
    i32x8 b1 = *(const i32x8*)(Wb + 2048);
    i32x8 b2 = *(const i32x8*)(Wb + 4096);
    i32x8 b3 = *(const i32x8*)(Wb + 6144);

    for (int dd = 0; dd < 84; dd++) {
        i32x8 n0 = *(const i32x8*)(Wb + 16384);
        i32x8 n1 = *(const i32x8*)(Wb + 16384 + 2048);
        i32x8 n2 = *(const i32x8*)(Wb + 16384 + 4096);
        i32x8 n3 = *(const i32x8*)(Wb + 16384 + 6144);

        int rem1 = rem + 1, a1 = a;
        if (rem1 == 26) { rem1 = 0; a1 = a + 1; }

        uint2 ja = jT[rem*65  + rl];
        uint2 jb = jT[rem1*65 + rl];
        float4 xa = iT[il + a];
        float4 xb = iT[il + a1];
        uint4 pa = lut16(tabS, xa, bflo(ja.x), bfhi(ja.x), bflo(ja.y));
        uint4 pb = lut16(tabS, xb, bflo(jb.x), bfhi(jb.x), bflo(jb.y));
        i32x8 A;
        A[0]=pa.x; A[1]=pa.y; A[2]=pa.z; A[3]=pa.w;
        A[4]=pb.x; A[5]=pb.y; A[6]=pb.z; A[7]=pb.w;
        acc[0] = __builtin_amdgcn_mfma_scale_f32_16x16x128_f8f6f4(A, b0, acc[0], 0, 0, 0, SCL1, 0, SCL1);
        acc[1] = __builtin_amdgcn_mfma_scale_f32_16x16x128_f8f6f4(A, b1, acc[1], 0, 0, 0, SCL1, 0, SCL1);
        acc[2] = __builtin_amdgcn_mfma_scale_f32_16x16x128_f8f6f4(A, b2, acc[2], 0, 0, 0, SCL1, 0, SCL1);
        acc[3] = __builtin_amdgcn_mfma_scale_f32_16x16x128_f8f6f4(A, b3, acc[3], 0, 0, 0, SCL1, 0, SCL1);

        b0 = n0; b1 = n1; b2 = n2; b3 = n3;
        Wb += 16384;
        rem += 8;
        if (rem >= 26) { rem -= 26; a += 1; }
    }

    {   // tail d=84: qd0 slots 672/673, qd1 674/675 (RBF); qd2 676(pos)/
        // 677(0); qd3 678/679 (0). b0..b3 hold block 84 from the pipeline.
        // State (a,rem) points at d=84; clamp a for safe reads.
        int rem1 = rem + 1, a1 = a;
        if (rem1 == 26) { rem1 = 0; a1 = a + 1; }
        int ac  = a  > 25 ? 25 : a;
        int a1c = a1 > 25 ? 25 : a1;

        uint2 ja = jT[rem*65  + rl];
        uint2 jb = jT[rem1*65 + rl];
        float4 xa = iT[il + ac];
        float4 xb = iT[il + a1c];
        uint4 pa = lut16(tabS, xa, bflo(ja.x), bfhi(ja.x), bflo(ja.y));
        uint4 pb = lut16(tabS, xb, bflo(jb.x), bfhi(jb.x), bflo(jb.y));

        if (qd == 2) {   // slot 676 = positional; 677 = zero
            int dcv;
            {
                int j  = JrowS[rl];
                int i_ = (bx*64 + rl) / TOPK;
                int off  = Ridx[i_] - Ridx[j];
                int same = (chain[i_] == chain[j]);
                int dc = off + 32; dc = dc < 0 ? 0 : (dc > 64 ? 64 : dc);
                dcv = same ? dc : 65;
            }
            float e[16];
            #pragma unroll
            for (int f = 0; f < 16; f++)
                e[f] = Wp[f*66 + dcv] + bp[f];
            int u0 = __builtin_amdgcn_cvt_pk_fp8_f32(e[0], e[1], 0, false);
            u0     = __builtin_amdgcn_cvt_pk_fp8_f32(e[2], e[3], u0, true);
            int u1 = __builtin_amdgcn_cvt_pk_fp8_f32(e[4], e[5], 0, false);
            u1     = __builtin_amdgcn_cvt_pk_fp8_f32(e[6], e[7], u1, true);
            int u2 = __builtin_amdgcn_cvt_pk_fp8_f32(e[8], e[9], 0, false);
            u2     = __builtin_amdgcn_cvt_pk_fp8_f32(e[10], e[11], u2, true);
            int u3 = __builtin_amdgcn_cvt_pk_fp8_f32(e[12], e[13], 0, false);
            u3     = __builtin_amdgcn_cvt_pk_fp8_f32(e[14], e[15], u3, true);
            pa = make_uint4((unsigned)u0,(unsigned)u1,(unsigned)u2,(unsigned)u3);
            pb = make_uint4(0,0,0,0);
        }
        if (qd == 3) {
            pa = make_uint4(0,0,0,0);
            pb = make_uint4(0,0,0,0);
        }

        i32x8 A;
        A[0]=pa.x; A[1]=pa.y; A[2]=pa.z; A[3]=pa.w;
        A[4]=pb.x; A[5]=pb.y; A[6]=pb.z; A[7]=pb.w;
        acc[0] = __builtin_amdgcn_mfma_scale_f32_16x16x128_f8f6f4(A, b0, acc[0], 0, 0, 0, SCL1, 0, SCL1);
        acc[1] = __builtin_amdgcn_mfma_scale_f32_16x16x128_f8f6f4(A, b1, acc[1], 0, 0, 0, SCL1, 0, SCL1);
        acc[2] = __builtin_amdgcn_mfma_scale_f32_16x16x128_f8f6f4(A, b2, acc[2], 0, 0, 0, SCL1, 0, SCL1);
        acc[3] = __builtin_amdgcn_mfma_scale_f32_16x16x128_f8f6f4(A, b3, acc[3], 0, 0, 0, SCL1, 0, SCL1);
    }

    // phase 2: acc -> LDS f32 [64][132] (overlay; jT/iT/tabS are dead).
    // D layout: col (within tile) = mlane, row = qd*4 + rr. Stride 132
    // makes the qd-groups land 16 banks apart -> 2-way (free).
    __syncthreads();
    #pragma unroll
    for (int nt = 0; nt < 4; nt++) {
        int col = (fg*4 + nt)*16 + mlane;
        #pragma unroll
        for (int rr = 0; rr < 4; rr++) {
            int r = rt*16 + qd*4 + rr;
            lnS[r*132 + col] = acc[nt][rr];
        }
    }
    __syncthreads();

    // in-block LayerNorm + final E write. Wave w handles rows w, w+8, ...
    for (int r = w; r < 64; r += 8) {
        float v0 = lnS[r*132 + 2*lane];
        float v1 = lnS[r*132 + 2*lane + 1];
        float S = v0 + v1, Q = v0*v0 + v1*v1;
        #pragma unroll
        for (int off = 32; off; off >>= 1) {
            S += __shfl_xor(S, off, 64);
            Q += __shfl_xor(Q, off, 64);
        }
        float mean = S * (1.0f/128.0f);
        float var  = Q * (1.0f/128.0f) - mean*mean;
        float rstd = rsqrtf(var + 1e-5f);
        float2 o;
        o.x = (v0 - mean) * rstd * ge[2*lane]   + be[2*lane];
        o.y = (v1 - mean) * rstd * ge[2*lane+1] + be[2*lane+1];
        ((float2*)(out + OUT_E))[(size_t)(bx*64 + r)*64 + lane] = o;
    }
}

// ------------------------------------------------------------------- launch --
extern "C" void kernel_launch(void* const* d_in, const int* in_sizes, int n_in,
                              void* d_out, int out_size, void* d_ws, size_t ws_size,
                              hipStream_t stream)
{
    const float* X     = (const float*)d_in[0];
    const int*   Ridx  = (const int*)d_in[2];
    const int*   chain = (const int*)d_in[3];
    const float* Xm    = (const float*)d_in[4];
    const float* prot  = (const float*)d_in[5];
    const float* dna   = (const float*)d_in[6];
    const float* rna   = (const float*)d_in[7];
    const int*   ptype = (const int*)d_in[8];
    const float* Wp    = (const float*)d_in[9];
    const float* bp    = (const float*)d_in[10];
    const float* We    = (const float*)d_in[11];
    const float* Wn    = (const float*)d_in[12];
    const float* ge    = (const float*)d_in[13];
    const float* be    = (const float*)d_in[14];
    const float* gn    = (const float*)d_in[15];
    const float* bn    = (const float*)d_in[16];
    char* ws = (char*)d_ws;
    float* out = (float*)d_out;

    kPrep<<<dim3(NRES + 384 + TBINS/256), dim3(256), 0, stream>>>(X, Xm, prot,
            dna, rna, ptype, Wn, gn, bn, We, ws, out);
    kC<<<dim3(MTOT/64), dim3(512), 0, stream>>>(Ridx, chain, Wp, bp, ge, be,
            ws, out);
}

// Round 10
// 150.557 us; speedup vs baseline: 1.0902x; 1.0902x over previous
//
#include <hip/hip_runtime.h>
#include <stdint.h>

// ---------------------------------------------------------------------------
// ProteinFeaturesNA on MI355X — R20: revert R19 (240-block all-K kC starved
// the chip: <1 block/CU, 1920 waves, occ 18%, kC 58us). Base = R18 (best,
// 148.9us: grid (240,4) x 4 waves, 2rt x 4frag split, W prefetch pipeline,
// 16KB LUT, mask baked into coords). Two low-risk adds:
//  (a) s_setprio(1/0) around each 4-MFMA cluster — kC waves are barrier-
//      free/desynced (attn-like regime where setprio measured +4-7%).
//  (b) kD: 2 rows/wave, uint2 loads (8B/lane), float4 stores, 32-lane
//      shuffle LN — kD was 4B/lane at 3.4 TB/s.
// Budget: fills ~88 (harness, fixed) + kC ~37 + kPrep ~10 + kD ~7 + gaps.
// Outputs (f32): V[512][128], E[15360][128], E_idx[15360].
// Dispatches: kPrep (aug/V-LN/top30 + W swizzle + LUT gen), kC, kD.
// ---------------------------------------------------------------------------

#define NRES   512
#define TOPK   30
#define NATOM  26
#define KTOT   10832
#define NBLK128 85            // 128-k blocks (padded K = 10880)
#define MTOT   (NRES*TOPK)    // 15360
#define NOUT   128
#define KSPLIT 4
#define TBINS  1024
#define TRANGE 25.6f          // Ds range covered by table; beyond -> zeros

#define OFF_AUGX4  0u          // 512*26 float4        = 212992
#define OFF_EIDX   212992u     // 512*30 i32           =  61440 -> 274432
#define OFF_WSWZ   274432u     // 85*8 frag * 2048 B   = 1392640 -> 1667072
#define OFF_EPART  1667072u    // <=6*15360*128 bf16 region (4 sets used)
#define OFF_TAB    25260032u   // 1024 * 16 B fp8 LUT  =    16384 -> 25276416

#define OUT_V     0
#define OUT_E     (NRES*NOUT)            // 65536
#define OUT_EIDX  (OUT_E + MTOT*NOUT)    // 2031616

typedef __attribute__((ext_vector_type(4))) float f32x4;
typedef __attribute__((ext_vector_type(8))) int   i32x8;

#define SA_C    0.96089792702915984f     // sqrt(log2 e)/1.25
#define MU0_C   1.9217958540583197f      // 2*SA
#define MUS_C   1.2811972360388798f      // (4/3)*SA
#define MUS2_C  (MUS_C*MUS_C)
#define SCL1    0x7f7f7f7f               // e8m0 unity scales (any opsel byte)
// LUT: bin = (int)(sqrt(d2) * SA * TBINS/TRANGE), clamped to TBINS-1.
#define TSCL    (SA_C * (float)TBINS / TRANGE)

__device__ __forceinline__ unsigned short f2bf(float f) {
    unsigned u = __builtin_bit_cast(unsigned, f);
    return (unsigned short)((u + 0x7fffu + ((u >> 16) & 1u)) >> 16);
}
__device__ __forceinline__ float bf2f(unsigned short u) {
    return __builtin_bit_cast(float, (unsigned)u << 16);
}
__device__ __forceinline__ float bflo(unsigned u) {
    return __builtin_bit_cast(float, u << 16);
}
__device__ __forceinline__ float bfhi(unsigned u) {
    return __builtin_bit_cast(float, u & 0xffff0000u);
}
__device__ __forceinline__ unsigned long long shfl_xor_u64(unsigned long long v, int m) {
    unsigned lo = (unsigned)v, hi = (unsigned)(v >> 32);
    lo = (unsigned)__shfl_xor((int)lo, m, 64);
    hi = (unsigned)__shfl_xor((int)hi, m, 64);
    return ((unsigned long long)hi << 32) | lo;
}
__device__ __forceinline__ float fexp2(float x) { return __builtin_amdgcn_exp2f(x); }
__device__ __forceinline__ float fsqrtf(float x) { return __builtin_amdgcn_sqrtf(x); }

// 16 RBF fp8 features of one slot via LDS LUT: one distance -> one b128 read.
// Bin TBINS-1 is all-zero in fp8. Masking is baked into coordinates:
// masked-j rows sit at -30000, masked-i atoms at +30000, so every masked
// pairing yields a huge distance -> fminf clamps to the last (zero) bin.
__device__ __forceinline__ uint4 lut16(const uint4* __restrict__ tabS,
                                       float4 xi, float jx, float jy, float jz) {
    float dx = xi.x - jx, dy = xi.y - jy, dz = xi.z - jz;
    float d2 = __builtin_fmaf(dx, dx, __builtin_fmaf(dy, dy,
               __builtin_fmaf(dz, dz, 1e-6f)));
    float fi = fsqrtf(d2) * TSCL;            // Ds * (TBINS/TRANGE)
    fi = fminf(fi, (float)(TBINS - 1));
    return tabS[(int)fi];
}

// -------------------------------------------------------------- kernel Prep --
// blocks [0,512): aug atoms + V-LN + top-30; blocks [512,896): W swizzle;
// blocks [896,900): RBF LUT generation (1024 bins x 16 fp8 feats).
// W fragment (K=128 layout): frag (d, nt) = 64 lanes x 32 B; lane
// (qd*16 + (n&15)) bytes cc*16+f = fp8 W[n][slot 8d+2qd+cc, feature f].
__global__ __launch_bounds__(256) void kPrep(
    const float* __restrict__ X, const float* __restrict__ Xm,
    const float* __restrict__ prot, const float* __restrict__ dna,
    const float* __restrict__ rna, const int* __restrict__ ptype,
    const float* __restrict__ Wn, const float* __restrict__ gn,
    const float* __restrict__ bn, const float* __restrict__ We,
    char* __restrict__ ws, float* __restrict__ out)
{
    if (blockIdx.x >= NRES + 384) {
        // LUT generation: one bin per thread. feature f = exp2(-(Ds-mu_f)^2),
        // mu_f = MU0 + f*MUS; Ds at bin center (b+0.5)*TRANGE/TBINS.
        int bb = (blockIdx.x - (NRES + 384)) * 256 + threadIdx.x;
        if (bb >= TBINS) return;
        float Ds = ((float)bb + 0.5f) * (TRANGE / (float)TBINS);
        unsigned r[4];
        #pragma unroll
        for (int g = 0; g < 4; g++) {
            float u0 = Ds - (MU0_C + (float)(4*g + 0) * MUS_C);
            float u1 = Ds - (MU0_C + (float)(4*g + 1) * MUS_C);
            float u2 = Ds - (MU0_C + (float)(4*g + 2) * MUS_C);
            float u3 = Ds - (MU0_C + (float)(4*g + 3) * MUS_C);
            float e0 = fexp2(-(u0 * u0));
            float e1 = fexp2(-(u1 * u1));
            float e2 = fexp2(-(u2 * u2));
            float e3 = fexp2(-(u3 * u3));
            int p = __builtin_amdgcn_cvt_pk_fp8_f32(e0, e1, 0, false);
            p     = __builtin_amdgcn_cvt_pk_fp8_f32(e2, e3, p, true);
            r[g] = (unsigned)p;
        }
        *(uint4*)(ws + OFF_TAB + (size_t)bb * 16) =
            make_uint4(r[0], r[1], r[2], r[3]);
        return;
    }
    if (blockIdx.x >= NRES) {
        int idx = blockIdx.x - NRES;
        int n = idx / 3;
        int s = (idx - n*3)*256 + threadIdx.x;
        if (s >= 677) return;
        const float* src = We + (size_t)n*KTOT + ((s < 676) ? (16 + s*16) : 0);
        float4 v0 = ((const float4*)src)[0];
        float4 v1 = ((const float4*)src)[1];
        float4 v2 = ((const float4*)src)[2];
        float4 v3 = ((const float4*)src)[3];
        int d = s >> 3, sl = s & 7, qd2 = sl >> 1, cc = sl & 1;
        size_t base = OFF_WSWZ
                    + (((size_t)(d*8 + (n >> 4))*64) + (size_t)(qd2*16 + (n & 15)))*32
                    + (size_t)cc*16;
        int r0 = __builtin_amdgcn_cvt_pk_fp8_f32(v0.x, v0.y, 0, false);
        r0     = __builtin_amdgcn_cvt_pk_fp8_f32(v0.z, v0.w, r0, true);
        int r1 = __builtin_amdgcn_cvt_pk_fp8_f32(v1.x, v1.y, 0, false);
        r1     = __builtin_amdgcn_cvt_pk_fp8_f32(v1.z, v1.w, r1, true);
        int r2 = __builtin_amdgcn_cvt_pk_fp8_f32(v2.x, v2.y, 0, false);
        r2     = __builtin_amdgcn_cvt_pk_fp8_f32(v2.z, v2.w, r2, true);
        int r3 = __builtin_amdgcn_cvt_pk_fp8_f32(v3.x, v3.y, 0, false);
        r3     = __builtin_amdgcn_cvt_pk_fp8_f32(v3.z, v3.w, r3, true);
        *(uint4*)(ws + base) = make_uint4((unsigned)r0, (unsigned)r1,
                                          (unsigned)r2, (unsigned)r3);
        return;
    }

    const int i = blockIdx.x, t = threadIdx.x;
    if (t >= 128) return;
    float4* augX4 = (float4*)(ws + OFF_AUGX4);
    int*    Eidx  = (int*)(ws + OFF_EIDX);
    const float* Xi = X + i * 72;

    if (t < 26) {
        float x, y, z, mk;
        if (t < 24) {
            x = Xi[t*3]; y = Xi[t*3+1]; z = Xi[t*3+2];
            mk = Xm[i*24 + t];
        } else if (t == 24) {
            float b0 = Xi[3]-Xi[0], b1 = Xi[4]-Xi[1], b2 = Xi[5]-Xi[2];
            float c0 = Xi[6]-Xi[3], c1 = Xi[7]-Xi[4], c2 = Xi[8]-Xi[5];
            float a0 = b1*c2-b2*c1, a1 = b2*c0-b0*c2, a2 = b0*c1-b1*c0;
            x = -0.58273431f*a0 + 0.56802827f*b0 - 0.54067466f*c0 + Xi[3];
            y = -0.58273431f*a1 + 0.56802827f*b1 - 0.54067466f*c1 + Xi[4];
            z = -0.58273431f*a2 + 0.56802827f*b2 - 0.54067466f*c2 + Xi[5];
            mk = prot[i];
        } else {
            const float* O4 = Xi + 33; const float* C1 = Xi + 45; const float* C2 = Xi + 42;
            float b0 = C1[0]-O4[0], b1 = C1[1]-O4[1], b2 = C1[2]-O4[2];
            float c0 = C2[0]-C1[0], c1 = C2[1]-C1[1], c2 = C2[2]-C1[2];
            float a0 = b1*c2-b2*c1, a1 = b2*c0-b0*c2, a2 = b0*c1-b1*c0;
            x = -0.56967352f*a0 + 0.51055973f*b0 - 0.53122153f*c0 + C1[0];
            y = -0.56967352f*a1 + 0.51055973f*b1 - 0.53122153f*c1 + C1[1];
            z = -0.56967352f*a2 + 0.51055973f*b2 - 0.53122153f*c2 + C1[2];
            mk = dna[i] + rna[i];
        }
        augX4[i*26 + t] = make_float4(x, y, z, mk);
    }

    // V layernorm (128 threads)
    __shared__ float red[4];
    int ty = ptype[i];
    float v = Wn[t*3 + ty];
    float s = v;
    #pragma unroll
    for (int off = 32; off; off >>= 1) s += __shfl_xor(s, off, 64);
    if ((t & 63) == 0) red[t>>6] = s;
    __syncthreads();
    float mean = (red[0] + red[1]) * (1.0f/128.0f);
    float d = v - mean;
    float s2 = d*d;
    #pragma unroll
    for (int off = 32; off; off >>= 1) s2 += __shfl_xor(s2, off, 64);
    if ((t & 63) == 0) red[2 + (t>>6)] = s2;
    __syncthreads();
    float var = (red[2] + red[3]) * (1.0f/128.0f);
    out[OUT_V + i*NOUT + t] = d * rsqrtf(var + 1e-5f) * gn[t] + bn[t];

    // top-30 (wave 0 only); Xc computed inline (bit-identical ops)
    if (t >= 64) return;
    const int l = t;
    float xi0 = Xi[3] + Xi[45], xi1 = Xi[4] + Xi[46], xi2 = Xi[5] + Xi[47];
    unsigned long long cand[8];
    #pragma unroll
    for (int sg = 0; sg < 8; sg++) {
        int j = sg*64 + l;
        const float* Xj = X + j*72;
        float c0 = Xj[3] + Xj[45], c1 = Xj[4] + Xj[46], c2 = Xj[5] + Xj[47];
        float dx = xi0 - c0, dy = xi1 - c1, dz = xi2 - c2;
        float dd = __fadd_rn(__fadd_rn(__fadd_rn(__fmul_rn(dx,dx), __fmul_rn(dy,dy)),
                                       __fmul_rn(dz,dz)), 1e-6f);
        float D = sqrtf(dd);
        cand[sg] = ((unsigned long long)__builtin_bit_cast(unsigned, D) << 32) | (unsigned)j;
    }
    for (int m = 0; m < TOPK; m++) {
        unsigned long long k = cand[0];
        #pragma unroll
        for (int sg = 1; sg < 8; sg++) if (cand[sg] < k) k = cand[sg];
        #pragma unroll
        for (int off = 32; off; off >>= 1) {
            unsigned long long o = shfl_xor_u64(k, off);
            if (o < k) k = o;
        }
        if (l == 0) {
            int j = (int)(k & 0xffffffffu);
            Eidx[i*TOPK + m] = j;
            out[OUT_EIDX + i*TOPK + m] = (float)j;
        }
        #pragma unroll
        for (int sg = 0; sg < 8; sg++) if (cand[sg] == k) cand[sg] = ~0ull;
    }
}

// ---------------------------------------------------------------- kernel C --
// grid (240, 4): block = 4 waves x 64 rows, K-quarter q. Wave w owns row
// tiles rtb=(w&1)*2 + {0,1} and col fragments fg=w>>1 -> f = fg*4 + nt
// (nt<4). Rows bx*64 + (rtb+rt)*16 + mlane; lane (mlane, qd) covers
// k = qd*32..+31 = slots 8d+2qd, +1 per 128-k block d. W loads software-
// pipelined (prefetch next d's b0..b3; tail reuses last prefetch).
// RBF features from 16 KB LDS LUT; masking baked into coords.
// s_setprio(1) wraps each 4-MFMA cluster (waves are barrier-free/desynced).
__global__ __launch_bounds__(256, 4) void kC(const int* __restrict__ Ridx,
                                             const int* __restrict__ chain,
                                             const float* __restrict__ Wp,
                                             const float* __restrict__ bp,
                                             char* __restrict__ ws)
{
    const int bx = blockIdx.x, q = blockIdx.y;
    const int t = threadIdx.x, lane = t & 63, w = t >> 6;
    const int mlane = lane & 15, qd = lane >> 4;
    const int rtb = (w & 1) * 2;          // row-tile base for this wave
    const int fg  = w >> 1;               // fragment group (4 frags)

    const float4* augX4 = (const float4*)(ws + OFF_AUGX4);
    const int*    Eidx  = (const int*)(ws + OFF_EIDX);
    unsigned short* Ep  = (unsigned short*)(ws + OFF_EPART)
                        + (size_t)q * MTOT * NOUT;

    __shared__ uint2  jT[NATOM * 65];     // 13520 B, stride-65 padded
    __shared__ float4 iT[5 * 26];         //  2080 B
    __shared__ int    JrowS[64];
    __shared__ uint4  tabS[TBINS];        // 16384 B RBF LUT

    if (t < 64) JrowS[t] = Eidx[bx*64 + t];
    __syncthreads();
    const int i_base = (bx*64) / TOPK;
    if (t < 5*26) {
        int il_ = t / 26, aa = t - il_*26;
        int gi = i_base + il_; gi = gi > 511 ? 511 : gi;
        float4 v = augX4[(size_t)gi*26 + aa];
        if (v.w == 0.0f) { v.x = 30000.0f; v.y = 30000.0f; v.z = 30000.0f; }
        iT[t] = v;
    }
    {   // stage LUT: 1024 x 16 B, coalesced (L2-resident)
        const uint4* tabG = (const uint4*)(ws + OFF_TAB);
        #pragma unroll
        for (int k = 0; k < 4; k++) tabS[t + k*256] = tabG[t + k*256];
    }
    for (int wk = t; wk < NATOM*64; wk += 256) {
        int aa = wk >> 6, rl_ = wk & 63;
        float4 p = augX4[(size_t)JrowS[rl_]*26 + aa];
        float x = p.x, y = p.y, z = p.z;
        if (p.w == 0.0f) { x = -30000.0f; y = -30000.0f; z = -30000.0f; }
        uint2 pk;
        pk.x = (unsigned)f2bf(x) | ((unsigned)f2bf(y) << 16);
        pk.y = (unsigned)f2bf(z);
        jT[aa*65 + rl_] = pk;
    }
    __syncthreads();

    // 2 row tiles: rows bx*64 + (rtb+rt)*16 + mlane
    int rl[2], il[2];
    #pragma unroll
    for (int rt = 0; rt < 2; rt++) {
        rl[rt] = (rtb + rt)*16 + mlane;
        il[rt] = ((bx*64 + rl[rt]) / TOPK - i_base) * 26;
    }

    f32x4 acc[2][4];   // [rt][nt]
    #pragma unroll
    for (int rt = 0; rt < 2; rt++)
        #pragma unroll
        for (int nt = 0; nt < 4; nt++)
            acc[rt][nt] = (f32x4){0.f,0.f,0.f,0.f};

    // K partition over 85 blocks: d0 = {0,22,43,64}, nmain = {22,21,21,20};
    // q==3 additionally handles the tail block d=84.
    const int d0 = (q == 0) ? 0 : (22 + (q-1)*21);
    const int nmain = (q == 0) ? 22 : ((q == 3) ? 20 : 21);

    // slot state: s = d*8 + 2*qd = a*26 + rem
    int s0i = d0*8 + 2*qd;
    int a = s0i / 26, rem = s0i - a*26;

    // wave reads fragments f = fg*4 + {0..3} (its 64 cols)
    const char* Wb = (const char*)(ws + OFF_WSWZ) + (size_t)d0*16384
                   + (size_t)(fg*4)*2048 + (size_t)lane*32;

    // software pipeline: b0..b3 hold block d0+dd; prefetch d0+dd+1 each
    // iter. Max prefetch block = d0+nmain <= 84 for every q; for q==3 the
    // post-loop registers hold exactly the tail block d=84.
    i32x8 b0 = *(const i32x8*)(Wb);
    i32x8 b1 = *(const i32x8*)(Wb + 2048);
    i32x8 b2 = *(const i32x8*)(Wb + 4096);
    i32x8 b3 = *(const i32x8*)(Wb + 6144);

    for (int dd = 0; dd < nmain; dd++) {
        i32x8 n0 = *(const i32x8*)(Wb + 16384);
        i32x8 n1 = *(const i32x8*)(Wb + 16384 + 2048);
        i32x8 n2 = *(const i32x8*)(Wb + 16384 + 4096);
        i32x8 n3 = *(const i32x8*)(Wb + 16384 + 6144);

        int rem1 = rem + 1, a1 = a;
        if (rem1 == 26) { rem1 = 0; a1 = a + 1; }

        #pragma unroll
        for (int rt = 0; rt < 2; rt++) {
            uint2 ja = jT[rem*65  + rl[rt]];
            uint2 jb = jT[rem1*65 + rl[rt]];
            float4 xa = iT[il[rt] + a];
            float4 xb = iT[il[rt] + a1];
            uint4 pa = lut16(tabS, xa, bflo(ja.x), bfhi(ja.x), bflo(ja.y));
            uint4 pb = lut16(tabS, xb, bflo(jb.x), bfhi(jb.x), bflo(jb.y));
            i32x8 A;
            A[0]=pa.x; A[1]=pa.y; A[2]=pa.z; A[3]=pa.w;
            A[4]=pb.x; A[5]=pb.y; A[6]=pb.z; A[7]=pb.w;
            __builtin_amdgcn_s_setprio(1);
            acc[rt][0] = __builtin_amdgcn_mfma_scale_f32_16x16x128_f8f6f4(A, b0, acc[rt][0], 0, 0, 0, SCL1, 0, SCL1);
            acc[rt][1] = __builtin_amdgcn_mfma_scale_f32_16x16x128_f8f6f4(A, b1, acc[rt][1], 0, 0, 0, SCL1, 0, SCL1);
            acc[rt][2] = __builtin_amdgcn_mfma_scale_f32_16x16x128_f8f6f4(A, b2, acc[rt][2], 0, 0, 0, SCL1, 0, SCL1);
            acc[rt][3] = __builtin_amdgcn_mfma_scale_f32_16x16x128_f8f6f4(A, b3, acc[rt][3], 0, 0, 0, SCL1, 0, SCL1);
            __builtin_amdgcn_s_setprio(0);
        }

        b0 = n0; b1 = n1; b2 = n2; b3 = n3;
        Wb += 16384;
        rem += 8;
        if (rem >= 26) { rem -= 26; a += 1; }
    }

    if (q == 3) {
        // tail d=84: qd0 slots 672/673, qd1 674/675 (RBF); qd2 676(pos)/677(0);
        // qd3 678/679 (0). b0..b3 already hold block 84 from the pipeline.
        // State (a,rem) points at d=84; clamp a for safe reads.
        int rem1 = rem + 1, a1 = a;
        if (rem1 == 26) { rem1 = 0; a1 = a + 1; }
        int ac  = a  > 25 ? 25 : a;
        int a1c = a1 > 25 ? 25 : a1;

        int dcv[2];
        if (qd == 2) {
            #pragma unroll
            for (int rt = 0; rt < 2; rt++) {
                int j  = JrowS[rl[rt]];
                int i_ = (bx*64 + rl[rt]) / TOPK;
                int off  = Ridx[i_] - Ridx[j];
                int same = (chain[i_] == chain[j]);
                int dc = off + 32; dc = dc < 0 ? 0 : (dc > 64 ? 64 : dc);
                dcv[rt] = same ? dc : 65;
            }
        }

        #pragma unroll
        for (int rt = 0; rt < 2; rt++) {
            uint2 ja = jT[rem*65  + rl[rt]];
            uint2 jb = jT[rem1*65 + rl[rt]];
            float4 xa = iT[il[rt] + ac];
            float4 xb = iT[il[rt] + a1c];
            uint4 pa = lut16(tabS, xa, bflo(ja.x), bfhi(ja.x), bflo(ja.y));
            uint4 pb = lut16(tabS, xb, bflo(jb.x), bfhi(jb.x), bflo(jb.y));

            if (qd == 2) {   // slot 676 = positional; 677 = zero
                float e[16];
                #pragma unroll
                for (int f = 0; f < 16; f++)
                    e[f] = Wp[f*66 + dcv[rt]] + bp[f];
                int u0 = __builtin_amdgcn_cvt_pk_fp8_f32(e[0], e[1], 0, false);
                u0     = __builtin_amdgcn_cvt_pk_fp8_f32(e[2], e[3], u0, true);
                int u1 = __builtin_amdgcn_cvt_pk_fp8_f32(e[4], e[5], 0, false);
                u1     = __builtin_amdgcn_cvt_pk_fp8_f32(e[6], e[7], u1, true);
                int u2 = __builtin_amdgcn_cvt_pk_fp8_f32(e[8], e[9], 0, false);
                u2     = __builtin_amdgcn_cvt_pk_fp8_f32(e[10], e[11], u2, true);
                int u3 = __builtin_amdgcn_cvt_pk_fp8_f32(e[12], e[13], 0, false);
                u3     = __builtin_amdgcn_cvt_pk_fp8_f32(e[14], e[15], u3, true);
                pa = make_uint4((unsigned)u0,(unsigned)u1,(unsigned)u2,(unsigned)u3);
                pb = make_uint4(0,0,0,0);
            }
            if (qd == 3) {
                pa = make_uint4(0,0,0,0);
                pb = make_uint4(0,0,0,0);
            }

            i32x8 A;
            A[0]=pa.x; A[1]=pa.y; A[2]=pa.z; A[3]=pa.w;
            A[4]=pb.x; A[5]=pb.y; A[6]=pb.z; A[7]=pb.w;
            __builtin_amdgcn_s_setprio(1);
            acc[rt][0] = __builtin_amdgcn_mfma_scale_f32_16x16x128_f8f6f4(A, b0, acc[rt][0], 0, 0, 0, SCL1, 0, SCL1);
            acc[rt][1] = __builtin_amdgcn_mfma_scale_f32_16x16x128_f8f6f4(A, b1, acc[rt][1], 0, 0, 0, SCL1, 0, SCL1);
            acc[rt][2] = __builtin_amdgcn_mfma_scale_f32_16x16x128_f8f6f4(A, b2, acc[rt][2], 0, 0, 0, SCL1, 0, SCL1);
            acc[rt][3] = __builtin_amdgcn_mfma_scale_f32_16x16x128_f8f6f4(A, b3, acc[rt][3], 0, 0, 0, SCL1, 0, SCL1);
            __builtin_amdgcn_s_setprio(0);
        }
    }

    // epilogue: bf16 partials. D layout: col (within tile) = mlane,
    // row = qd*4 + rr. Global col = (fg*4+nt)*16 + mlane.
    #pragma unroll
    for (int rt = 0; rt < 2; rt++) {
        #pragma unroll
        for (int nt = 0; nt < 4; nt++) {
            int col = (fg*4 + nt)*16 + mlane;
            #pragma unroll
            for (int rr = 0; rr < 4; rr++) {
                int g0 = bx*64 + (rtb + rt)*16 + qd*4 + rr;
                Ep[(size_t)g0*NOUT + col] = f2bf(acc[rt][nt][rr]);
            }
        }
    }
}

// ---------------------------------------------------------------- kernel D --
// 2 rows per wave: lanes 0-31 row A, lanes 32-63 row B. uint2 (8B/lane)
// loads of bf16 partials, 32-lane shuffle LN, float4 stores.
__global__ __launch_bounds__(256) void kD(const float* __restrict__ ge,
                                          const float* __restrict__ be,
                                          char* __restrict__ ws,
                                          float* __restrict__ out)
{
    const uint2* Ep2 = (const uint2*)(ws + OFF_EPART);
    const int t = threadIdx.x, wv = t >> 6, lane = t & 63;
    const int half = lane >> 5, hl = lane & 31;
    const int row = blockIdx.x*8 + wv*2 + half;
    const size_t qs2 = (size_t)MTOT * 32;          // uint2 per partial set
    size_t b = (size_t)row*32 + hl;

    float v0 = 0.f, v1 = 0.f, v2 = 0.f, v3 = 0.f;
    #pragma unroll
    for (int qq = 0; qq < KSPLIT; qq++) {
        uint2 u = Ep2[b + (size_t)qq*qs2];
        v0 += bf2f((unsigned short)(u.x & 0xffffu));
        v1 += bf2f((unsigned short)(u.x >> 16));
        v2 += bf2f((unsigned short)(u.y & 0xffffu));
        v3 += bf2f((unsigned short)(u.y >> 16));
    }

    float S = v0 + v1 + v2 + v3;
    float Q = v0*v0 + v1*v1 + v2*v2 + v3*v3;
    #pragma unroll
    for (int off = 16; off; off >>= 1) {   // xor<=16 stays within 32-lane half
        S += __shfl_xor(S, off, 64);
        Q += __shfl_xor(Q, off, 64);
    }
    float mean = S * (1.0f/128.0f);
    float var  = Q * (1.0f/128.0f) - mean*mean;
    float rstd = rsqrtf(var + 1e-5f);
    int c0 = hl*4;
    float4 o;
    o.x = (v0 - mean) * rstd * ge[c0]   + be[c0];
    o.y = (v1 - mean) * rstd * ge[c0+1] + be[c0+1];
    o.z = (v2 - mean) * rstd * ge[c0+2] + be[c0+2];
    o.w = (v3 - mean) * rstd * ge[c0+3] + be[c0+3];
    ((float4*)(out + OUT_E))[(size_t)row*32 + hl] = o;
}

// ------------------------------------------------------------------- launch --
extern "C" void kernel_launch(void* const* d_in, const int* in_sizes, int n_in,
                              void* d_out, int out_size, void* d_ws, size_t ws_size,
                              hipStream_t stream)
{
    const float* X     = (const float*)d_in[0];
    const int*   Ridx  = (const int*)d_in[2];
    const int*   chain = (const int*)d_in[3];
    const float* Xm    = (const float*)d_in[4];
    const float* prot  = (const float*)d_in[5];
    const float* dna   = (const float*)d_in[6];
    const float* rna   = (const float*)d_in[7];
    const int*   ptype = (const int*)d_in[8];
    const float* Wp    = (const float*)d_in[9];
    const float* bp    = (const float*)d_in[10];
    const float* We    = (const float*)d_in[11];
    const float* Wn    = (const float*)d_in[12];
    const float* ge    = (const float*)d_in[13];
    const float* be    = (const float*)d_in[14];
    const float* gn    = (const float*)d_in[15];
    const float* bn    = (const float*)d_in[16];
    char* ws = (char*)d_ws;
    float* out = (float*)d_out;

    kPrep<<<dim3(NRES + 384 + TBINS/256), dim3(256), 0, stream>>>(X, Xm, prot,
            dna, rna, ptype, Wn, gn, bn, We, ws, out);
    kC<<<dim3(240, KSPLIT), dim3(256), 0, stream>>>(Ridx, chain, Wp, bp, ws);
    kD<<<dim3(MTOT/8), dim3(256), 0, stream>>>(ge, be, ws, out);
}